// Round 3
// baseline (373.781 us; speedup 1.0000x reference)
//
#include <hip/hip_runtime.h>

// GraphAttentionLayer: out = softmax(mask(beta * cos_sim(x,x), adj)) @ x
// N=8192, D=128, density 0.005 (~41 neighbors/row incl. self-loop).
//
// Sparse formulation: exp(-1e9) == 0.0f exactly in fp32 -> non-neighbors drop
// out. |score| < beta < 1 -> exp can't over/underflow -> no max pass.
//
// SPLIT DESIGN (R3): the fused kernel convoyed phases and let the 268 MB adj
// stream evict x from L2/L3, pushing x-gathers to HBM.
//  K1 scan: pure streaming compaction of adj rows -> per-row index lists in
//           d_ws (+ row norms, fused). Memory-bound at the 268 MB adj floor.
//  K2 agg : score + weighted-accumulate from the index lists. Touches only
//           x (4 MB) + idx (4 MB) + norms (32 KB) -> fully cache-resident.

#define GN 8192
#define GD 128
#define WPB 4            // waves (rows) per 256-thread block
#define MAXN 128         // index slots per row (max observed nnz ~80)
#define BUF 160          // LDS compaction buffer per wave (slack, never hit)

typedef float f32x4 __attribute__((ext_vector_type(4)));

__global__ __launch_bounds__(256, 8) void scan_kernel(
    const float* __restrict__ x, const float* __restrict__ adj,
    float* __restrict__ norms, int* __restrict__ cnts, int* __restrict__ idxg) {
    __shared__ int idxb[WPB][BUF];

    int wid = threadIdx.x >> 6, lane = threadIdx.x & 63;
    int row = blockIdx.x * WPB + wid;
    int* my = idxb[wid];
    const float* arow = adj + (size_t)row * GN;

    // fused row-norm (hides under the adj stream's memory waits)
    float2 u = *(const float2*)(x + (size_t)row * GD + lane * 2);
    float ns = u.x * u.x + u.y * u.y;
    #pragma unroll
    for (int m = 32; m; m >>= 1) ns += __shfl_xor(ns, m, 64);
    if (lane == 0) norms[row] = sqrtf(ns);

    // rolling prefetch, 3 chunks (3 KB/wave) in flight, nontemporal
    f32x4 a0 = __builtin_nontemporal_load((const f32x4*)(arow + 0 * 256 + lane * 4));
    f32x4 a1 = __builtin_nontemporal_load((const f32x4*)(arow + 1 * 256 + lane * 4));
    f32x4 a2 = __builtin_nontemporal_load((const f32x4*)(arow + 2 * 256 + lane * 4));

    int cnt = 0;   // wave-uniform (from ballots)
    for (int chunk = 0; chunk < 32; ++chunk) {
        int pc = chunk + 3; if (pc > 31) pc = 31;   // clamped (no branch)
        f32x4 an = __builtin_nontemporal_load(
            (const f32x4*)(arow + pc * 256 + lane * 4));
        int col0 = chunk * 256 + lane * 4;
        #pragma unroll
        for (int c = 0; c < 4; ++c) {
            bool nz = (a0[c] != 0.f);
            unsigned long long m = __ballot(nz);
            int off = __builtin_amdgcn_mbcnt_hi((unsigned)(m >> 32),
                      __builtin_amdgcn_mbcnt_lo((unsigned)m, 0));
            if (nz) my[cnt + off] = col0 + c;
            cnt += __popcll(m);
        }
        a0 = a1; a1 = a2; a2 = an;
    }

    if (cnt > MAXN) cnt = MAXN;   // unreachable safety clamp
    __builtin_amdgcn_wave_barrier();
    int* grow = idxg + (size_t)row * MAXN;
    if (lane < cnt)      grow[lane]      = my[lane];
    if (64 + lane < cnt) grow[64 + lane] = my[64 + lane];
    if (lane == 0) cnts[row] = cnt;
}

__global__ __launch_bounds__(256, 8) void agg_kernel(
    const float* __restrict__ x, const float* __restrict__ beta_p,
    const float* __restrict__ norms, const int* __restrict__ cnts,
    const int* __restrict__ idxg, float* __restrict__ out) {
    __shared__ int idxb[WPB][MAXN + 4];

    int wid = threadIdx.x >> 6, lane = threadIdx.x & 63;
    int row = blockIdx.x * WPB + wid;
    int* my = idxb[wid];

    int cnt = cnts[row];                      // same addr all lanes -> broadcast
    const int* grow = idxg + (size_t)row * MAXN;
    if (lane < cnt)      my[lane]      = grow[lane];
    if (64 + lane < cnt) my[64 + lane] = grow[64 + lane];
    if (lane < 4) my[cnt + lane] = row;       // sentinels for unroll-4 tail
    __builtin_amdgcn_wave_barrier();

    float2 u = *(const float2*)(x + (size_t)row * GD + lane * 2);
    float beta = beta_p[0];
    float ni = norms[row];

    float2 acc = {0.f, 0.f};
    float denom = 0.f;                        // wave-uniform (butterflies bit-identical)

    for (int k = 0; k < cnt; k += 4) {
        int jj[4]; float2 v[4]; float d[4];
        #pragma unroll
        for (int t = 0; t < 4; ++t) jj[t] = my[k + t];        // LDS broadcast
        #pragma unroll
        for (int t = 0; t < 4; ++t)
            v[t] = *(const float2*)(x + (size_t)jj[t] * GD + lane * 2);  // coalesced, L2-hit
        #pragma unroll
        for (int t = 0; t < 4; ++t)
            d[t] = v[t].x * u.x + v[t].y * u.y;
        #pragma unroll
        for (int m = 32; m; m >>= 1) {                        // 4 interleaved butterflies
            #pragma unroll
            for (int t = 0; t < 4; ++t) d[t] += __shfl_xor(d[t], m, 64);
        }
        #pragma unroll
        for (int t = 0; t < 4; ++t) {
            float nj = norms[jj[t]];                          // uniform addr -> broadcast
            float s = beta * d[t] * __builtin_amdgcn_rcpf(ni * nj + 1e-7f);
            float p = __expf(s);
            p = (k + t < cnt) ? p : 0.f;
            acc.x += p * v[t].x;
            acc.y += p * v[t].y;
            denom += p;
        }
    }

    float inv = 1.0f / denom;
    float2 o = {acc.x * inv, acc.y * inv};
    *(float2*)(out + (size_t)row * GD + lane * 2) = o;
}

extern "C" void kernel_launch(void* const* d_in, const int* in_sizes, int n_in,
                              void* d_out, int out_size, void* d_ws, size_t ws_size,
                              hipStream_t stream) {
    const float* x    = (const float*)d_in[0];
    const float* adj  = (const float*)d_in[1];
    const float* beta = (const float*)d_in[2];
    float* out = (float*)d_out;

    // ws layout: norms [8192 f] | cnts [8192 i] | idx [8192*128 i] = 4.06 MB
    float* norms = (float*)d_ws;
    int*   cnts  = (int*)((char*)d_ws + GN * sizeof(float));
    int*   idxg  = (int*)((char*)d_ws + 2 * GN * sizeof(float));

    scan_kernel<<<GN / WPB, 256, 0, stream>>>(x, adj, norms, cnts, idxg);
    agg_kernel<<<GN / WPB, 256, 0, stream>>>(x, beta, norms, cnts, idxg, out);
}